// Round 3
// baseline (49.087 us; speedup 1.0000x reference)
//
#include <hip/hip_runtime.h>
#include <float.h>

#define NS 50
#define NP 64              // padded to power of two for bitonic network
#define B_DIM 8192
#define D_DIM 64
#define BD (B_DIM * D_DIM)
#define BLOCK 256

// min 4 waves/EU -> VGPR cap ~128: enough room to keep all 50 loads in
// flight (MLP), still 16 waves/CU for latency hiding.
__global__ __launch_bounds__(BLOCK, 4) void energy_score_kernel(
    const float* __restrict__ mean,
    const float* __restrict__ variance,
    const float* __restrict__ noise,
    const float* __restrict__ target,
    float* __restrict__ out) {

    const int idx = blockIdx.x * BLOCK + threadIdx.x;

    const float m = mean[idx];
    const float v = variance[idx];
    const float t = target[idx];
    const float sd = sqrtf(v + 1e-6f);

    // ---- Phase 1: pure load loop. 50 independent dword loads into distinct
    // registers, no consumer in between -> compiler can issue all of them
    // before the first s_waitcnt (maximum memory-level parallelism).
    float s[NP];
    const float* np_ = noise + idx;
    #pragma unroll
    for (int k = 0; k < NS; ++k) {
        s[k] = np_[(size_t)k * BD];
    }

    // ---- Phase 2: sample construction + first term (2 accumulator chains).
    float f0 = 0.0f, f1 = 0.0f;
    #pragma unroll
    for (int k = 0; k < NS; ++k) {
        s[k] = fmaf(s[k], sd, m);
        float d = fabsf(s[k] - t);
        if (k & 1) f1 += d;
        else       f0 += d;
    }
    #pragma unroll
    for (int k = NS; k < NP; ++k) s[k] = FLT_MAX;

    // ---- Phase 3: bitonic sort network, 64 elems, fully unrolled.
    // All indices/directions compile-time -> pure v_min_f32/v_max_f32;
    // FLT_MAX padding entries constant-fold away in early stages.
    #pragma unroll
    for (int k = 2; k <= NP; k <<= 1) {
        #pragma unroll
        for (int j = k >> 1; j > 0; j >>= 1) {
            #pragma unroll
            for (int i = 0; i < NP; ++i) {
                const int l = i ^ j;
                if (l > i) {
                    const bool up = ((i & k) == 0);
                    float a = s[i], b = s[l];
                    float lo = fminf(a, b);
                    float hi = fmaxf(a, b);
                    s[i] = up ? lo : hi;   // compile-time select
                    s[l] = up ? hi : lo;
                }
            }
        }
    }

    // ---- Phase 4: sum_{i<j}|s_i-s_j| == sum_k (2k-(n-1)) * sorted_k.
    float p0 = 0.0f, p1 = 0.0f;
    #pragma unroll
    for (int k = 0; k < NS; ++k) {
        const float c = (float)(2 * k - (NS - 1));
        if (k & 1) p1 = fmaf(c, s[k], p1);
        else       p0 = fmaf(c, s[k], p0);
    }

    // energy = first/NS - 0.5*pair/(NS*(NS-1)/2); pre-scale by 1/BD for mean
    float e = (f0 + f1) * (1.0f / NS) - (p0 + p1) * (1.0f / 2450.0f);
    e *= (1.0f / (float)BD);

    // ---- Phase 5: reduction. 64-lane wave shuffle, LDS across waves,
    // one atomic per block.
    #pragma unroll
    for (int off = 32; off > 0; off >>= 1)
        e += __shfl_down(e, off, 64);

    __shared__ float wsum[BLOCK / 64];
    const int lane = threadIdx.x & 63;
    const int wid  = threadIdx.x >> 6;
    if (lane == 0) wsum[wid] = e;
    __syncthreads();

    if (threadIdx.x == 0) {
        float bs = 0.0f;
        #pragma unroll
        for (int w = 0; w < BLOCK / 64; ++w) bs += wsum[w];
        atomicAdd(out, bs);
    }
}

extern "C" void kernel_launch(void* const* d_in, const int* in_sizes, int n_in,
                              void* d_out, int out_size, void* d_ws, size_t ws_size,
                              hipStream_t stream) {
    const float* mean     = (const float*)d_in[0];
    const float* variance = (const float*)d_in[1];
    const float* noise    = (const float*)d_in[2];
    const float* target   = (const float*)d_in[3];
    float* out = (float*)d_out;

    // d_out is poisoned before timing and not re-zeroed between replays.
    hipMemsetAsync(out, 0, sizeof(float), stream);

    const int grid = BD / BLOCK;  // 2048 blocks
    energy_score_kernel<<<grid, BLOCK, 0, stream>>>(mean, variance, noise, target, out);
}

// Round 4
// 48.799 us; speedup vs baseline: 1.0059x; 1.0059x over previous
//
#include <hip/hip_runtime.h>
#include <float.h>

#define NS 50
#define NP 64              // padded to power of two for bitonic network
#define B_DIM 8192
#define D_DIM 64
#define BD (B_DIM * D_DIM)
#define BLOCK 256

typedef const __attribute__((address_space(1))) float gfloat;
typedef __attribute__((address_space(3))) float lfloat;

// 3 waves/EU min -> 3 blocks/CU (matches the 50KB-LDS limit), VGPR cap ~168.
__global__ __launch_bounds__(BLOCK, 3) void energy_score_kernel(
    const float* __restrict__ mean,
    const float* __restrict__ variance,
    const float* __restrict__ noise,
    const float* __restrict__ target,
    float* __restrict__ out) {

    __shared__ float tile[NS * BLOCK];       // 50 rows x 256 floats = 50 KB

    const int tid  = threadIdx.x;
    const int lane = tid & 63;
    const int wid  = tid >> 6;
    const size_t blockOff = (size_t)blockIdx.x * BLOCK;

    // ---- Async stage: global -> LDS, fire-and-forget, no VGPR destinations.
    // Wave w stages rows k = w, w+4, ... (k wave-uniform). Each instruction
    // moves 64 lanes x 16B = 1KB = one full row. ~13 loads in flight per wave.
    for (int k = wid; k < NS; k += 4) {
        gfloat* g = (gfloat*)(noise + (size_t)k * BD + blockOff + (size_t)lane * 4);
        lfloat* l = (lfloat*)(tile + k * BLOCK);   // wave-uniform base; HW adds lane*16B
        __builtin_amdgcn_global_load_lds(g, l, 16, 0, 0);
    }

    const int idx = (int)blockOff + tid;
    const float m = mean[idx];
    const float v = variance[idx];
    const float t = target[idx];
    const float sd = sqrtf(v + 1e-6f);

    __syncthreads();   // compiler emits vmcnt(0) drain + barrier

    // ---- Samples from LDS column tid (consecutive lanes -> free 2-way
    // bank aliasing) + first term with 2 accumulator chains.
    float s[NP];
    float f0 = 0.0f, f1 = 0.0f;
    #pragma unroll
    for (int k = 0; k < NS; ++k) {
        float nz = tile[k * BLOCK + tid];
        s[k] = fmaf(nz, sd, m);
        float d = fabsf(s[k] - t);
        if (k & 1) f1 += d;
        else       f0 += d;
    }
    #pragma unroll
    for (int k = NS; k < NP; ++k) s[k] = FLT_MAX;

    // ---- Bitonic sort network, 64 elems, fully unrolled (verified R2/R3).
    #pragma unroll
    for (int k = 2; k <= NP; k <<= 1) {
        #pragma unroll
        for (int j = k >> 1; j > 0; j >>= 1) {
            #pragma unroll
            for (int i = 0; i < NP; ++i) {
                const int l = i ^ j;
                if (l > i) {
                    const bool up = ((i & k) == 0);
                    float a = s[i], b = s[l];
                    float lo = fminf(a, b);
                    float hi = fmaxf(a, b);
                    s[i] = up ? lo : hi;   // compile-time select
                    s[l] = up ? hi : lo;
                }
            }
        }
    }

    // ---- Pair term via sort identity: sum_k (2k-(n-1)) * sorted_k.
    float p0 = 0.0f, p1 = 0.0f;
    #pragma unroll
    for (int k = 0; k < NS; ++k) {
        const float c = (float)(2 * k - (NS - 1));
        if (k & 1) p1 = fmaf(c, s[k], p1);
        else       p0 = fmaf(c, s[k], p0);
    }

    // energy = first/NS - 0.5*pair/(NS*(NS-1)/2); pre-scale by 1/BD for mean
    float e = (f0 + f1) * (1.0f / NS) - (p0 + p1) * (1.0f / 2450.0f);
    e *= (1.0f / (float)BD);

    // ---- Reduction: 64-lane shuffle, LDS across waves, 1 atomic per block.
    #pragma unroll
    for (int off = 32; off > 0; off >>= 1)
        e += __shfl_down(e, off, 64);

    __shared__ float wsum[BLOCK / 64];
    if (lane == 0) wsum[wid] = e;
    __syncthreads();

    if (tid == 0) {
        float bs = 0.0f;
        #pragma unroll
        for (int w = 0; w < BLOCK / 64; ++w) bs += wsum[w];
        atomicAdd(out, bs);
    }
}

extern "C" void kernel_launch(void* const* d_in, const int* in_sizes, int n_in,
                              void* d_out, int out_size, void* d_ws, size_t ws_size,
                              hipStream_t stream) {
    const float* mean     = (const float*)d_in[0];
    const float* variance = (const float*)d_in[1];
    const float* noise    = (const float*)d_in[2];
    const float* target   = (const float*)d_in[3];
    float* out = (float*)d_out;

    // d_out is poisoned before timing and not re-zeroed between replays.
    hipMemsetAsync(out, 0, sizeof(float), stream);

    const int grid = BD / BLOCK;  // 2048 blocks
    energy_score_kernel<<<grid, BLOCK, 0, stream>>>(mean, variance, noise, target, out);
}

// Round 5
// 40.797 us; speedup vs baseline: 1.2032x; 1.1961x over previous
//
#include <hip/hip_runtime.h>
#include <float.h>

#define NS 50
#define NP 64              // padded to power of two for bitonic network
#define B_DIM 8192
#define D_DIM 64
#define BD (B_DIM * D_DIM)
#define BLOCK 256
#define GRID (BD / BLOCK)  // 2048

// ---- Core per-element pipeline (verified R2-R4): returns pre-scaled energy.
__device__ __forceinline__ float energy_elem(const float* __restrict__ mean,
                                             const float* __restrict__ variance,
                                             const float* __restrict__ noise,
                                             const float* __restrict__ target,
                                             int idx) {
    const float m = mean[idx];
    const float v = variance[idx];
    const float t = target[idx];
    const float sd = sqrtf(v + 1e-6f);

    float s[NP];
    const float* np_ = noise + idx;
    #pragma unroll
    for (int k = 0; k < NS; ++k) s[k] = np_[(size_t)k * BD];

    float f0 = 0.0f, f1 = 0.0f;
    #pragma unroll
    for (int k = 0; k < NS; ++k) {
        s[k] = fmaf(s[k], sd, m);
        float d = fabsf(s[k] - t);
        if (k & 1) f1 += d;
        else       f0 += d;
    }
    #pragma unroll
    for (int k = NS; k < NP; ++k) s[k] = FLT_MAX;

    // Bitonic sort network, 64 elems, fully unrolled, compile-time dirs.
    #pragma unroll
    for (int k = 2; k <= NP; k <<= 1) {
        #pragma unroll
        for (int j = k >> 1; j > 0; j >>= 1) {
            #pragma unroll
            for (int i = 0; i < NP; ++i) {
                const int l = i ^ j;
                if (l > i) {
                    const bool up = ((i & k) == 0);
                    float a = s[i], b = s[l];
                    float lo = fminf(a, b);
                    float hi = fmaxf(a, b);
                    s[i] = up ? lo : hi;
                    s[l] = up ? hi : lo;
                }
            }
        }
    }

    // sum_{i<j}|s_i-s_j| == sum_k (2k-(n-1)) * sorted_k
    float p0 = 0.0f, p1 = 0.0f;
    #pragma unroll
    for (int k = 0; k < NS; ++k) {
        const float c = (float)(2 * k - (NS - 1));
        if (k & 1) p1 = fmaf(c, s[k], p1);
        else       p0 = fmaf(c, s[k], p0);
    }

    float e = (f0 + f1) * (1.0f / NS) - (p0 + p1) * (1.0f / 2450.0f);
    return e * (1.0f / (float)BD);   // pre-scale for global mean
}

__device__ __forceinline__ float block_reduce(float e, int tid) {
    #pragma unroll
    for (int off = 32; off > 0; off >>= 1)
        e += __shfl_down(e, off, 64);
    __shared__ float wsum[BLOCK / 64];
    const int lane = tid & 63;
    const int wid  = tid >> 6;
    if (lane == 0) wsum[wid] = e;
    __syncthreads();
    float bs = 0.0f;
    if (tid == 0) {
        #pragma unroll
        for (int w = 0; w < BLOCK / 64; ++w) bs += wsum[w];
    }
    return bs;
}

// Stage 1: per-block partial sum -> plain store to ws (NO atomics).
__global__ __launch_bounds__(BLOCK) void energy_partial_kernel(
    const float* __restrict__ mean, const float* __restrict__ variance,
    const float* __restrict__ noise, const float* __restrict__ target,
    float* __restrict__ partial) {
    const int idx = blockIdx.x * BLOCK + threadIdx.x;
    float e = energy_elem(mean, variance, noise, target, idx);
    float bs = block_reduce(e, threadIdx.x);
    if (threadIdx.x == 0) partial[blockIdx.x] = bs;
}

// Stage 2: one block sums the 2048 partials, writes the scalar output.
__global__ __launch_bounds__(BLOCK) void reduce_partial_kernel(
    const float* __restrict__ partial, float* __restrict__ out) {
    float e = 0.0f;
    #pragma unroll
    for (int i = 0; i < GRID / BLOCK; ++i)
        e += partial[i * BLOCK + threadIdx.x];
    float bs = block_reduce(e, threadIdx.x);
    if (threadIdx.x == 0) out[0] = bs;   // overwrites poison; no memset needed
}

// Fallback (ws too small): old single-kernel atomic path.
__global__ __launch_bounds__(BLOCK) void energy_atomic_kernel(
    const float* __restrict__ mean, const float* __restrict__ variance,
    const float* __restrict__ noise, const float* __restrict__ target,
    float* __restrict__ out) {
    const int idx = blockIdx.x * BLOCK + threadIdx.x;
    float e = energy_elem(mean, variance, noise, target, idx);
    float bs = block_reduce(e, threadIdx.x);
    if (threadIdx.x == 0) atomicAdd(out, bs);
}

extern "C" void kernel_launch(void* const* d_in, const int* in_sizes, int n_in,
                              void* d_out, int out_size, void* d_ws, size_t ws_size,
                              hipStream_t stream) {
    const float* mean     = (const float*)d_in[0];
    const float* variance = (const float*)d_in[1];
    const float* noise    = (const float*)d_in[2];
    const float* target   = (const float*)d_in[3];
    float* out = (float*)d_out;

    if (ws_size >= (size_t)GRID * sizeof(float)) {
        float* partial = (float*)d_ws;
        energy_partial_kernel<<<GRID, BLOCK, 0, stream>>>(mean, variance, noise,
                                                          target, partial);
        reduce_partial_kernel<<<1, BLOCK, 0, stream>>>(partial, out);
    } else {
        hipMemsetAsync(out, 0, sizeof(float), stream);
        energy_atomic_kernel<<<GRID, BLOCK, 0, stream>>>(mean, variance, noise,
                                                         target, out);
    }
}